// Round 5
// baseline (285.401 us; speedup 1.0000x reference)
//
#include <hip/hip_runtime.h>
#include <stdint.h>

#define N_ROWS 16384
#define DIM    512

typedef float v4f __attribute__((ext_vector_type(4)));
typedef unsigned long long u64;
typedef unsigned char u8;

// Monotonic float -> sortable u32 key
__device__ __forceinline__ unsigned fkey(float f) {
    unsigned u = __float_as_uint(f);
    return (u & 0x80000000u) ? ~u : (u | 0x80000000u);
}

// Async global->LDS, 16B per lane. LDS dest = wave-uniform base + lane*16.
__device__ __forceinline__ void gload_lds16(const void* g, void* l) {
    __builtin_amdgcn_global_load_lds(
        (const __attribute__((address_space(1))) unsigned int*)g,
        (__attribute__((address_space(3))) unsigned int*)l,
        16, 0, 0);
}

// ---------------- kernel 1: fp32 -> fp8 e4m3 convert (+ table & out zero-init) ----------------
// HW RNE; x ~ N(0,1), e4m3 max 448 -> no saturation. Validated (absmax 0.0).
// Zeroes the scalar output here (no separate hipMemsetAsync dispatch).
__global__ __launch_bounds__(256)
void convert_fp8_kernel(const float* __restrict__ x, unsigned* __restrict__ x8,
                        u64* __restrict__ table, float* __restrict__ out) {
    int tid    = blockIdx.x * blockDim.x + threadIdx.x;
    int stride = gridDim.x * blockDim.x;
    if (tid == 0) *out = 0.f;
    if (tid < N_ROWS) table[tid] = 0;
    const float4* x4 = (const float4*)x;
    const int n4 = (N_ROWS * DIM) / 4;
    for (int i = tid; i < n4; i += stride) {
        float4 v = x4[i];
        int b = __builtin_amdgcn_cvt_pk_fp8_f32(v.x, v.y, 0, false);   // bytes 0,1
        b     = __builtin_amdgcn_cvt_pk_fp8_f32(v.z, v.w, b, true);    // bytes 2,3
        x8[i] = (unsigned)b;
    }
}

// ---------------- kernel 2: symmetric tiled fp8 GEMM + fused argmax ----------------
// PROVEN structure (174 us, MfmaUtil 33.5 / VALUBusy 42.4 / occ 31.9 --
// the m97-structure ceiling signature). Measured-refuted alternatives:
//  * r9  8-wave 256^2 phase-split w/ counted vmcnt: 233 us (coarse-split trap
//    m196 + 1 block/CU occupancy).
//  * r10 MX-scaled K=128 MFMA (scale=1.0): 316 us (MFMA pipe hit its 28 us
//    floor but +64 live VGPRs collapsed occupancy 31.8->11.5; barrier drain
//    became the naked critical path).
//  * r12 cooperative-fused 3-phase kernel: container failure (harness
//    incompatibility -- no hipLaunchCooperativeKernel in this harness).
//
// Triangle-fold schedule: b = u*64 + p; u<=p -> (127-p,127-u), else (p,u-1).
// LDS layout per matrix (16 KB, swizzle at 16-fp8 chunks): tile = 128 rows
// x 128 k-bytes = 128 x 8 chunks. Slot (row, sk) holds chunk kc = sk ^ (row&7).
//  * staging lane L: row=L>>3, sk=L&7 -> src kc=(L&7)^(row&7); 8-lane groups
//    load full 128 B rows -> coalesced.
//  * frag read (k-step s, quad q, lane15 l): wants 8 B at kc=2s+(q>>1), half
//    q&1 of row rf*16+l -> addr = row*128 + ((2s+(q>>1))^(l&7))*16 + (q&1)*8.
//    ds_read_b64 natural 16-lane phases: banks (c^(l&7))*4+2(q&1) -> 2-way
//    aliasing = free (m136).
__global__ __launch_bounds__(256)
void argmax_dots_kernel(const u8* __restrict__ xb, u64* __restrict__ table) {
    __shared__ __attribute__((aligned(16))) u8 ldsA[128 * 128];  // 16 KB
    __shared__ __attribute__((aligned(16))) u8 ldsB[128 * 128];  // 16 KB

    const int u = blockIdx.x >> 6;
    const int p = blockIdx.x & 63;
    const int rT = (u <= p) ? (127 - p) : p;
    const int cT = (u <= p) ? (127 - u) : (u - 1);

    const int t      = threadIdx.x;
    const int lane   = t & 63;
    const int wave   = t >> 6;
    const int lane15 = lane & 15;
    const int quad   = lane >> 4;
    const int rh = wave >> 1;               // row half of the 128x128 tile
    const int ch = wave & 1;                // col half

    const int rowBase = rT * 128;
    const int colBase = cT * 128;

    // Staging sources: 4 issues per matrix per round, coalesced row-major.
    const u8* gA[4];
    const u8* gB[4];
#pragma unroll
    for (int j = 0; j < 4; ++j) {
        const int L   = j * 256 + t;
        const int row = L >> 3;
        const int kc  = (L & 7) ^ (row & 7);       // swizzled source chunk
        gA[j] = xb + (size_t)(rowBase + row) * DIM + kc * 16;
        gB[j] = xb + (size_t)(colBase + row) * DIM + kc * 16;
    }
    const int dstOff = wave * 1024;         // + j*4096 per issue (bytes)

    // Per-lane frag address pieces: addr = base + rf*2048 + xorK[s]
    const int aBase = (rh * 64 + lane15) * 128 + (quad & 1) * 8;
    const int bBase = (ch * 64 + lane15) * 128 + (quad & 1) * 8;
    int xorK[4];
#pragma unroll
    for (int s = 0; s < 4; ++s)
        xorK[s] = ((2 * s + (quad >> 1)) ^ (lane15 & 7)) << 4;

    v4f acc[4][4];
#pragma unroll
    for (int rf = 0; rf < 4; ++rf)
#pragma unroll
        for (int cf = 0; cf < 4; ++cf) {
            v4f z = {0.f, 0.f, 0.f, 0.f};
            acc[rf][cf] = z;
        }

#pragma unroll
    for (int k = 0; k < 4; ++k) {           // 4 K-rounds of BK=128
        const int kk = k * 128;             // byte offset within a row
#pragma unroll
        for (int j = 0; j < 4; ++j) {
            gload_lds16(gA[j] + kk, (char*)ldsA + j * 4096 + dstOff);
            gload_lds16(gB[j] + kk, (char*)ldsB + j * 4096 + dstOff);
        }
        __syncthreads();                    // drains vmcnt; loads visible

#pragma unroll
        for (int s = 0; s < 4; ++s) {       // 4 k-steps of 32 fp8
            const int xs = xorK[s];
            long a8[4], b8[4];
#pragma unroll
            for (int rf = 0; rf < 4; ++rf)
                a8[rf] = *(const long*)(ldsA + aBase + rf * 2048 + xs);
#pragma unroll
            for (int cf = 0; cf < 4; ++cf)
                b8[cf] = *(const long*)(ldsB + bBase + cf * 2048 + xs);
#pragma unroll
            for (int rf = 0; rf < 4; ++rf)
#pragma unroll
                for (int cf = 0; cf < 4; ++cf)
                    acc[rf][cf] = __builtin_amdgcn_mfma_f32_16x16x32_fp8_fp8(
                        a8[rf], b8[cf], acc[rf][cf], 0, 0, 0);
        }
        __syncthreads();                    // protect LDS from next round's writes
    }

    // ---- epilogue: row-side argmax (C/D layout: col=lane15+16*cf, row=quad*4+e) ----
    const int colLane = colBase + ch * 64 + lane15;
#pragma unroll
    for (int rf = 0; rf < 4; ++rf) {
#pragma unroll
        for (int e = 0; e < 4; ++e) {
            const int row = rowBase + rh * 64 + rf * 16 + quad * 4 + e;
            float bv = -3.0e38f;
            int   bc = 0;
#pragma unroll
            for (int cf = 0; cf < 4; ++cf) {
                const float v = acc[rf][cf][e];
                const int col = colLane + cf * 16;
                if (v > bv && col != row) { bv = v; bc = col; }
            }
            u64 packed = ((u64)fkey(bv) << 32) | (unsigned)(~bc);  // ~col: ties->lowest idx
#pragma unroll
            for (int m = 1; m < 16; m <<= 1) {
                u64 o = __shfl_xor(packed, m, 64);
                if (o > packed) packed = o;
            }
            if (lane15 == 0) atomicMax(&table[row], packed);
        }
    }

    // ---- epilogue: col-side (transposed) argmax for off-diagonal tiles ----
    if (rT != cT) {
#pragma unroll
        for (int cf = 0; cf < 4; ++cf) {
            const int col = colLane + cf * 16;
            float bv = -3.0e38f;
            int   br_ = 0;
#pragma unroll
            for (int rf = 0; rf < 4; ++rf)
#pragma unroll
                for (int e = 0; e < 4; ++e) {
                    const float v = acc[rf][cf][e];
                    const int row = rowBase + rh * 64 + rf * 16 + quad * 4 + e;
                    if (v > bv) { bv = v; br_ = row; }
                }
            u64 packed = ((u64)fkey(bv) << 32) | (unsigned)(~br_);
            u64 o = __shfl_xor(packed, 16, 64); if (o > packed) packed = o;
            o     = __shfl_xor(packed, 32, 64); if (o > packed) packed = o;
            if (quad == 0) atomicMax(&table[col], packed);
        }
    }
}

// ---------------- kernel 3: rho + loss epilogue (fp32 exact) ----------------
// 1024 blocks x 4 rows/wave: 4096 waves for this latency-bound loop
// (dependent table->row loads + 6-level shuffle chain per row).
__global__ __launch_bounds__(256)
void rho_loss_kernel(const float* __restrict__ x, const u64* __restrict__ table,
                     float* __restrict__ out) {
    const int lane = threadIdx.x & 63;
    const int wave = threadIdx.x >> 6;
    const int waveGlobal = blockIdx.x * 4 + wave;   // 4096 waves

    float local = 0.f;
    for (int r4 = 0; r4 < 4; ++r4) {
        const int row = waveGlobal * 4 + r4;
        const u64 packed = table[row];
        const int nb = (int)(~(unsigned)(packed & 0xFFFFFFFFu));

        const float4* xr = (const float4*)(x + (size_t)row * DIM);
        const float4* xn = (const float4*)(x + (size_t)nb  * DIM);
        float s = 0.f;
#pragma unroll
        for (int tt = 0; tt < 2; ++tt) {
            float4 a = xr[lane * 2 + tt];
            float4 b = xn[lane * 2 + tt];
            float d0 = a.x - b.x + 1e-6f;
            float d1 = a.y - b.y + 1e-6f;
            float d2 = a.z - b.z + 1e-6f;
            float d3 = a.w - b.w + 1e-6f;
            s += d0 * d0 + d1 * d1 + d2 * d2 + d3 * d3;
        }
#pragma unroll
        for (int m = 1; m < 64; m <<= 1) s += __shfl_xor(s, m, 64);

        if (lane == 0) {
            float rho = sqrtf(s);
            local += logf(rho + 1e-8f);
        }
    }
    if (lane == 0) atomicAdd(out, -local * (1.0f / 16384.0f));
}

extern "C" void kernel_launch(void* const* d_in, const int* in_sizes, int n_in,
                              void* d_out, int out_size, void* d_ws, size_t ws_size,
                              hipStream_t stream) {
    const float* x = (const float*)d_in[0];

    // Workspace: [0, 8 MiB) fp8 x; then 16384 x u64 argmax table.
    u8*    xb    = (u8*)d_ws;
    u64*   table = (u64*)((char*)d_ws + (size_t)N_ROWS * DIM);
    float* out   = (float*)d_out;

    convert_fp8_kernel<<<2048, 256, 0, stream>>>(x, (unsigned*)xb, table, out);
    argmax_dots_kernel<<<8256, 256, 0, stream>>>(xb, table);
    rho_loss_kernel<<<1024, 256, 0, stream>>>(x, table, out);
}

// Round 6
// 243.176 us; speedup vs baseline: 1.1736x; 1.1736x over previous
//
#include <hip/hip_runtime.h>
#include <stdint.h>

#define N_ROWS 16384
#define DIM    512

typedef float v4f __attribute__((ext_vector_type(4)));
typedef unsigned long long u64;
typedef unsigned char u8;

// Monotonic float -> sortable u32 key
__device__ __forceinline__ unsigned fkey(float f) {
    unsigned u = __float_as_uint(f);
    return (u & 0x80000000u) ? ~u : (u | 0x80000000u);
}

// Async global->LDS, 16B per lane. LDS dest = wave-uniform base + lane*16.
__device__ __forceinline__ void gload_lds16(const void* g, void* l) {
    __builtin_amdgcn_global_load_lds(
        (const __attribute__((address_space(1))) unsigned int*)g,
        (__attribute__((address_space(3))) unsigned int*)l,
        16, 0, 0);
}

// ---------------- kernel 1: fp32 -> fp8 e4m3 convert (+ table & out zero-init) ----------------
// HW RNE; x ~ N(0,1), e4m3 max 448 -> no saturation. Validated (absmax 0.0).
// Zeroes the scalar output here (no separate hipMemsetAsync dispatch).
__global__ __launch_bounds__(256)
void convert_fp8_kernel(const float* __restrict__ x, unsigned* __restrict__ x8,
                        u64* __restrict__ table, float* __restrict__ out) {
    int tid    = blockIdx.x * blockDim.x + threadIdx.x;
    int stride = gridDim.x * blockDim.x;
    if (tid == 0) *out = 0.f;
    if (tid < N_ROWS) table[tid] = 0;
    const float4* x4 = (const float4*)x;
    const int n4 = (N_ROWS * DIM) / 4;
    for (int i = tid; i < n4; i += stride) {
        float4 v = x4[i];
        int b = __builtin_amdgcn_cvt_pk_fp8_f32(v.x, v.y, 0, false);   // bytes 0,1
        b     = __builtin_amdgcn_cvt_pk_fp8_f32(v.z, v.w, b, true);    // bytes 2,3
        x8[i] = (unsigned)b;
    }
}

// ---------------- kernel 2: symmetric tiled fp8 GEMM + fused argmax ----------------
// PROVEN structure (172-178 us, MfmaUtil 33.4 / VALUBusy 42.4 / occ 31.9 --
// the m97-structure ceiling signature, stable across 3 sessions).
// Measured-refuted alternatives on this problem:
//  * r9  8-wave 256^2 phase-split w/ counted vmcnt: 233 us (coarse-split trap
//    m196 + 1 block/CU occupancy).
//  * r10 MX-scaled K=128 MFMA (scale=1.0): 316 us (MFMA pipe hit its 28 us
//    floor but +64 live VGPRs collapsed occupancy 31.8->11.5; barrier drain
//    became the naked critical path).
//  * r12 cooperative-fused 3-phase kernel: container failure (no
//    hipLaunchCooperativeKernel in this harness).
//
// Triangle-fold schedule: b = u*64 + p; u<=p -> (127-p,127-u), else (p,u-1).
// LDS layout per matrix (16 KB, swizzle at 16-fp8 chunks): tile = 128 rows
// x 128 k-bytes = 128 x 8 chunks. Slot (row, sk) holds chunk kc = sk ^ (row&7).
//  * staging lane L: row=L>>3, sk=L&7 -> src kc=(L&7)^(row&7); 8-lane groups
//    load full 128 B rows -> coalesced.
//  * frag read (k-step s, quad q, lane15 l): wants 8 B at kc=2s+(q>>1), half
//    q&1 of row rf*16+l -> addr = row*128 + ((2s+(q>>1))^(l&7))*16 + (q&1)*8.
//    ds_read_b64 natural 16-lane phases: banks (c^(l&7))*4+2(q&1) -> 2-way
//    aliasing = free (m136).
__global__ __launch_bounds__(256)
void argmax_dots_kernel(const u8* __restrict__ xb, u64* __restrict__ table) {
    __shared__ __attribute__((aligned(16))) u8 ldsA[128 * 128];  // 16 KB
    __shared__ __attribute__((aligned(16))) u8 ldsB[128 * 128];  // 16 KB

    const int u = blockIdx.x >> 6;
    const int p = blockIdx.x & 63;
    const int rT = (u <= p) ? (127 - p) : p;
    const int cT = (u <= p) ? (127 - u) : (u - 1);

    const int t      = threadIdx.x;
    const int lane   = t & 63;
    const int wave   = t >> 6;
    const int lane15 = lane & 15;
    const int quad   = lane >> 4;
    const int rh = wave >> 1;               // row half of the 128x128 tile
    const int ch = wave & 1;                // col half

    const int rowBase = rT * 128;
    const int colBase = cT * 128;

    // Staging sources: 4 issues per matrix per round, coalesced row-major.
    const u8* gA[4];
    const u8* gB[4];
#pragma unroll
    for (int j = 0; j < 4; ++j) {
        const int L   = j * 256 + t;
        const int row = L >> 3;
        const int kc  = (L & 7) ^ (row & 7);       // swizzled source chunk
        gA[j] = xb + (size_t)(rowBase + row) * DIM + kc * 16;
        gB[j] = xb + (size_t)(colBase + row) * DIM + kc * 16;
    }
    const int dstOff = wave * 1024;         // + j*4096 per issue (bytes)

    // Per-lane frag address pieces: addr = base + rf*2048 + xorK[s]
    const int aBase = (rh * 64 + lane15) * 128 + (quad & 1) * 8;
    const int bBase = (ch * 64 + lane15) * 128 + (quad & 1) * 8;
    int xorK[4];
#pragma unroll
    for (int s = 0; s < 4; ++s)
        xorK[s] = ((2 * s + (quad >> 1)) ^ (lane15 & 7)) << 4;

    v4f acc[4][4];
#pragma unroll
    for (int rf = 0; rf < 4; ++rf)
#pragma unroll
        for (int cf = 0; cf < 4; ++cf) {
            v4f z = {0.f, 0.f, 0.f, 0.f};
            acc[rf][cf] = z;
        }

#pragma unroll
    for (int k = 0; k < 4; ++k) {           // 4 K-rounds of BK=128
        const int kk = k * 128;             // byte offset within a row
#pragma unroll
        for (int j = 0; j < 4; ++j) {
            gload_lds16(gA[j] + kk, (char*)ldsA + j * 4096 + dstOff);
            gload_lds16(gB[j] + kk, (char*)ldsB + j * 4096 + dstOff);
        }
        __syncthreads();                    // drains vmcnt; loads visible

#pragma unroll
        for (int s = 0; s < 4; ++s) {       // 4 k-steps of 32 fp8
            const int xs = xorK[s];
            long a8[4], b8[4];
#pragma unroll
            for (int rf = 0; rf < 4; ++rf)
                a8[rf] = *(const long*)(ldsA + aBase + rf * 2048 + xs);
#pragma unroll
            for (int cf = 0; cf < 4; ++cf)
                b8[cf] = *(const long*)(ldsB + bBase + cf * 2048 + xs);
#pragma unroll
            for (int rf = 0; rf < 4; ++rf)
#pragma unroll
                for (int cf = 0; cf < 4; ++cf)
                    acc[rf][cf] = __builtin_amdgcn_mfma_f32_16x16x32_fp8_fp8(
                        a8[rf], b8[cf], acc[rf][cf], 0, 0, 0);
        }
        __syncthreads();                    // protect LDS from next round's writes
    }

    // ---- epilogue: row-side argmax (C/D layout: col=lane15+16*cf, row=quad*4+e) ----
    const int colLane = colBase + ch * 64 + lane15;
#pragma unroll
    for (int rf = 0; rf < 4; ++rf) {
#pragma unroll
        for (int e = 0; e < 4; ++e) {
            const int row = rowBase + rh * 64 + rf * 16 + quad * 4 + e;
            float bv = -3.0e38f;
            int   bc = 0;
#pragma unroll
            for (int cf = 0; cf < 4; ++cf) {
                const float v = acc[rf][cf][e];
                const int col = colLane + cf * 16;
                if (v > bv && col != row) { bv = v; bc = col; }
            }
            u64 packed = ((u64)fkey(bv) << 32) | (unsigned)(~bc);  // ~col: ties->lowest idx
#pragma unroll
            for (int m = 1; m < 16; m <<= 1) {
                u64 o = __shfl_xor(packed, m, 64);
                if (o > packed) packed = o;
            }
            if (lane15 == 0) atomicMax(&table[row], packed);
        }
    }

    // ---- epilogue: col-side (transposed) argmax for off-diagonal tiles ----
    if (rT != cT) {
#pragma unroll
        for (int cf = 0; cf < 4; ++cf) {
            const int col = colLane + cf * 16;
            float bv = -3.0e38f;
            int   br_ = 0;
#pragma unroll
            for (int rf = 0; rf < 4; ++rf)
#pragma unroll
                for (int e = 0; e < 4; ++e) {
                    const float v = acc[rf][cf][e];
                    const int row = rowBase + rh * 64 + rf * 16 + quad * 4 + e;
                    if (v > bv) { bv = v; br_ = row; }
                }
            u64 packed = ((u64)fkey(bv) << 32) | (unsigned)(~br_);
            u64 o = __shfl_xor(packed, 16, 64); if (o > packed) packed = o;
            o     = __shfl_xor(packed, 32, 64); if (o > packed) packed = o;
            if (quad == 0) atomicMax(&table[col], packed);
        }
    }
}

// ---------------- kernel 3: rho + loss epilogue (fp32 exact) ----------------
// r13: the r11 "2x parallelism" rho (4096 waves, 4096 same-address atomics)
// regressed the total by a reproducible +20 us (r0=265.3 vs r3/r5=285.3/285.4
// with identical argmax counters) -- same-address atomicAdd serializes in one
// TCC channel and is the un-hideable kernel tail. Fix: back to 512 blocks x
// 8 rows/wave (r0 shape) + block-level LDS reduction -> 512 atomics total
// (4x fewer than r0, 8x fewer than r11). Table loads prefetched (independent
// -> all in flight) ahead of the dependent xn chains.
__global__ __launch_bounds__(256)
void rho_loss_kernel(const float* __restrict__ x, const u64* __restrict__ table,
                     float* __restrict__ out) {
    __shared__ float partial[4];
    const int lane = threadIdx.x & 63;
    const int wave = threadIdx.x >> 6;
    const int waveGlobal = blockIdx.x * 4 + wave;   // 2048 waves

    u64 pk[8];
#pragma unroll
    for (int r8 = 0; r8 < 8; ++r8) pk[r8] = table[waveGlobal * 8 + r8];

    float local = 0.f;
#pragma unroll
    for (int r8 = 0; r8 < 8; ++r8) {
        const int row = waveGlobal * 8 + r8;
        const int nb  = (int)(~(unsigned)(pk[r8] & 0xFFFFFFFFu));

        const float4* xr = (const float4*)(x + (size_t)row * DIM);
        const float4* xn = (const float4*)(x + (size_t)nb  * DIM);
        float s = 0.f;
#pragma unroll
        for (int tt = 0; tt < 2; ++tt) {
            float4 a = xr[lane * 2 + tt];
            float4 b = xn[lane * 2 + tt];
            float d0 = a.x - b.x + 1e-6f;
            float d1 = a.y - b.y + 1e-6f;
            float d2 = a.z - b.z + 1e-6f;
            float d3 = a.w - b.w + 1e-6f;
            s += d0 * d0 + d1 * d1 + d2 * d2 + d3 * d3;
        }
#pragma unroll
        for (int m = 1; m < 64; m <<= 1) s += __shfl_xor(s, m, 64);

        if (lane == 0) {
            float rho = sqrtf(s);
            local += logf(rho + 1e-8f);
        }
    }
    if (lane == 0) partial[wave] = local;
    __syncthreads();
    if (threadIdx.x == 0) {
        const float s = partial[0] + partial[1] + partial[2] + partial[3];
        atomicAdd(out, -s * (1.0f / 16384.0f));
    }
}

extern "C" void kernel_launch(void* const* d_in, const int* in_sizes, int n_in,
                              void* d_out, int out_size, void* d_ws, size_t ws_size,
                              hipStream_t stream) {
    const float* x = (const float*)d_in[0];

    // Workspace: [0, 8 MiB) fp8 x; then 16384 x u64 argmax table.
    u8*    xb    = (u8*)d_ws;
    u64*   table = (u64*)((char*)d_ws + (size_t)N_ROWS * DIM);
    float* out   = (float*)d_out;

    convert_fp8_kernel<<<2048, 256, 0, stream>>>(x, (unsigned*)xb, table, out);
    argmax_dots_kernel<<<8256, 256, 0, stream>>>(xb, table);
    rho_loss_kernel<<<512, 256, 0, stream>>>(x, table, out);
}

// Round 7
// 230.286 us; speedup vs baseline: 1.2393x; 1.0560x over previous
//
#include <hip/hip_runtime.h>
#include <stdint.h>

#define N_ROWS 16384
#define DIM    512

typedef float v4f __attribute__((ext_vector_type(4)));
typedef long  v2l __attribute__((ext_vector_type(2)));
typedef unsigned long long u64;
typedef unsigned char u8;

// Monotonic float -> sortable u32 key
__device__ __forceinline__ unsigned fkey(float f) {
    unsigned u = __float_as_uint(f);
    return (u & 0x80000000u) ? ~u : (u | 0x80000000u);
}

// Async global->LDS, 16B per lane. LDS dest = wave-uniform base + lane*16.
__device__ __forceinline__ void gload_lds16(const void* g, void* l) {
    __builtin_amdgcn_global_load_lds(
        (const __attribute__((address_space(1))) unsigned int*)g,
        (__attribute__((address_space(3))) unsigned int*)l,
        16, 0, 0);
}

// ---------------- kernel 1: fp32 -> fp8 e4m3 convert + K-PERMUTE (+ zero-init) ----------------
// HW RNE; x ~ N(0,1), e4m3 max 448 -> no saturation (absmax 0.0 proven).
// r14: writes xb in a PERMUTED K-layout so kernel 2 can fragment-read with
// ds_read_b128 instead of 2x ds_read_b64 (whose lanes l / l+8 structurally
// 2-way bank-conflict: same lane15&7 -> same swizzle slot -> same bank pair;
// 1.69e7 conflict cycles/dispatch = ~27 us/CU of LDS stall).
// Per row, per 128-B K-round block: new 16-B chunk c' = 2q+h holds old bytes
// [64h+8q, +8) ++ [64h+32+8q, +8)  (the step-2h and step-2h+1 operands of
// lane-quad q). For float4 word w of a row (d = 4w):
//   kr=w>>5, s=(w>>3)&3, q=(w>>1)&3, h=s>>1, half=s&1
//   new word = r*128 + kr*32 + (2q+h)*4 + half*2 + (w&1)
__global__ __launch_bounds__(256)
void convert_fp8_kernel(const float* __restrict__ x, unsigned* __restrict__ x8,
                        u64* __restrict__ table, float* __restrict__ out) {
    int tid    = blockIdx.x * blockDim.x + threadIdx.x;
    int stride = gridDim.x * blockDim.x;
    if (tid == 0) *out = 0.f;
    if (tid < N_ROWS) table[tid] = 0;
    const float4* x4 = (const float4*)x;
    const int n4 = (N_ROWS * DIM) / 4;
    for (int i = tid; i < n4; i += stride) {
        float4 v = x4[i];
        int b = __builtin_amdgcn_cvt_pk_fp8_f32(v.x, v.y, 0, false);   // bytes 0,1
        b     = __builtin_amdgcn_cvt_pk_fp8_f32(v.z, v.w, b, true);    // bytes 2,3
        const int r  = i >> 7;              // row (128 words/row)
        const int w  = i & 127;
        const int kr = w >> 5;              // K-round
        const int s  = (w >> 3) & 3;        // k-step within round
        const int q  = (w >> 1) & 3;        // lane quad owning these 8 dims
        const int h  = s >> 1;
        const int hf = s & 1;
        x8[r * 128 + kr * 32 + (2 * q + h) * 4 + hf * 2 + (w & 1)] = (unsigned)b;
    }
}

// ---------------- kernel 2: symmetric tiled fp8 GEMM + fused argmax ----------------
// PROVEN schedule (m97-ceiling signature 33.5/42.4/31.9, stable over 4 runs).
// Measured-refuted alternatives: r9 8-wave phase-split (233 us), r10 MX-scaled
// MFMA (316 us), r12 cooperative fusion (harness failure).
// r14 change: fragment reads are ds_read_b128 on the permuted layout -- one
// b128 per (rf|cf, h) yields BOTH k-step operands (low/high 8B). 16-lane b128
// phase = 256B = 2 cycles minimum, so the 2-way slot aliasing is schedulable
// conflict-free (vs b64: 1-cycle phase -> every read paid 2x). Halves LDS
// instruction count and read-address VALU.
// Staging is BYTE-IDENTICAL to the proven version: it moves opaque 16-B
// chunks through the same slot swizzle sk = c' ^ (row&7); only the chunk
// CONTENTS are permuted (consistently produced by kernel 1, consumed here).
__global__ __launch_bounds__(256)
void argmax_dots_kernel(const u8* __restrict__ xb, u64* __restrict__ table) {
    __shared__ __attribute__((aligned(16))) u8 ldsA[128 * 128];  // 16 KB
    __shared__ __attribute__((aligned(16))) u8 ldsB[128 * 128];  // 16 KB

    const int u = blockIdx.x >> 6;
    const int p = blockIdx.x & 63;
    const int rT = (u <= p) ? (127 - p) : p;
    const int cT = (u <= p) ? (127 - u) : (u - 1);

    const int t      = threadIdx.x;
    const int lane   = t & 63;
    const int wave   = t >> 6;
    const int lane15 = lane & 15;
    const int quad   = lane >> 4;
    const int rh = wave >> 1;               // row half of the 128x128 tile
    const int ch = wave & 1;                // col half

    const int rowBase = rT * 128;
    const int colBase = cT * 128;

    // Staging sources: 4 issues per matrix per round, coalesced row-major.
    const u8* gA[4];
    const u8* gB[4];
#pragma unroll
    for (int j = 0; j < 4; ++j) {
        const int L   = j * 256 + t;
        const int row = L >> 3;
        const int kc  = (L & 7) ^ (row & 7);       // swizzled source chunk
        gA[j] = xb + (size_t)(rowBase + row) * DIM + kc * 16;
        gB[j] = xb + (size_t)(colBase + row) * DIM + kc * 16;
    }
    const int dstOff = wave * 1024;         // + j*4096 per issue (bytes)

    // Per-lane frag addresses: row base + rf*2048 + slot-xor (per h)
    const int aBase = (rh * 64 + lane15) * 128;
    const int bBase = (ch * 64 + lane15) * 128;
    int xorH[2];
#pragma unroll
    for (int h = 0; h < 2; ++h)
        xorH[h] = ((2 * quad + h) ^ (lane15 & 7)) << 4;

    v4f acc[4][4];
#pragma unroll
    for (int rf = 0; rf < 4; ++rf)
#pragma unroll
        for (int cf = 0; cf < 4; ++cf) {
            v4f z = {0.f, 0.f, 0.f, 0.f};
            acc[rf][cf] = z;
        }

#pragma unroll
    for (int k = 0; k < 4; ++k) {           // 4 K-rounds of BK=128
        const int kk = k * 128;             // byte offset within a row
#pragma unroll
        for (int j = 0; j < 4; ++j) {
            gload_lds16(gA[j] + kk, (char*)ldsA + j * 4096 + dstOff);
            gload_lds16(gB[j] + kk, (char*)ldsB + j * 4096 + dstOff);
        }
        __syncthreads();                    // drains vmcnt; loads visible

#pragma unroll
        for (int h = 0; h < 2; ++h) {       // 2 half-rounds; each = 2 k-steps
            const int xs = xorH[h];
            v2l a2[4], b2[4];
#pragma unroll
            for (int rf = 0; rf < 4; ++rf)
                a2[rf] = *(const v2l*)(ldsA + aBase + rf * 2048 + xs);
#pragma unroll
            for (int cf = 0; cf < 4; ++cf)
                b2[cf] = *(const v2l*)(ldsB + bBase + cf * 2048 + xs);
            // k-step 2h: low 8B of each chunk
#pragma unroll
            for (int rf = 0; rf < 4; ++rf)
#pragma unroll
                for (int cf = 0; cf < 4; ++cf)
                    acc[rf][cf] = __builtin_amdgcn_mfma_f32_16x16x32_fp8_fp8(
                        a2[rf][0], b2[cf][0], acc[rf][cf], 0, 0, 0);
            // k-step 2h+1: high 8B
#pragma unroll
            for (int rf = 0; rf < 4; ++rf)
#pragma unroll
                for (int cf = 0; cf < 4; ++cf)
                    acc[rf][cf] = __builtin_amdgcn_mfma_f32_16x16x32_fp8_fp8(
                        a2[rf][1], b2[cf][1], acc[rf][cf], 0, 0, 0);
        }
        __syncthreads();                    // protect LDS from next round's writes
    }

    // ---- epilogue: row-side argmax (C/D layout: col=lane15+16*cf, row=quad*4+e) ----
    const int colLane = colBase + ch * 64 + lane15;
#pragma unroll
    for (int rf = 0; rf < 4; ++rf) {
#pragma unroll
        for (int e = 0; e < 4; ++e) {
            const int row = rowBase + rh * 64 + rf * 16 + quad * 4 + e;
            float bv = -3.0e38f;
            int   bc = 0;
#pragma unroll
            for (int cf = 0; cf < 4; ++cf) {
                const float v = acc[rf][cf][e];
                const int col = colLane + cf * 16;
                if (v > bv && col != row) { bv = v; bc = col; }
            }
            u64 packed = ((u64)fkey(bv) << 32) | (unsigned)(~bc);  // ~col: ties->lowest idx
#pragma unroll
            for (int m = 1; m < 16; m <<= 1) {
                u64 o = __shfl_xor(packed, m, 64);
                if (o > packed) packed = o;
            }
            if (lane15 == 0) atomicMax(&table[row], packed);
        }
    }

    // ---- epilogue: col-side (transposed) argmax for off-diagonal tiles ----
    if (rT != cT) {
#pragma unroll
        for (int cf = 0; cf < 4; ++cf) {
            const int col = colLane + cf * 16;
            float bv = -3.0e38f;
            int   br_ = 0;
#pragma unroll
            for (int rf = 0; rf < 4; ++rf)
#pragma unroll
                for (int e = 0; e < 4; ++e) {
                    const float v = acc[rf][cf][e];
                    const int row = rowBase + rh * 64 + rf * 16 + quad * 4 + e;
                    if (v > bv) { bv = v; br_ = row; }
                }
            u64 packed = ((u64)fkey(bv) << 32) | (unsigned)(~br_);
            u64 o = __shfl_xor(packed, 16, 64); if (o > packed) packed = o;
            o     = __shfl_xor(packed, 32, 64); if (o > packed) packed = o;
            if (quad == 0) atomicMax(&table[col], packed);
        }
    }
}

// ---------------- kernel 3: rho + loss epilogue (fp32 exact) ----------------
// r13-proven (243 us total): 512 blocks x 8 rows/wave, table prefetch,
// block-level LDS reduction -> 512 same-address atomics (the 4096-atomic
// variant cost a reproducible +20 us of serialized tail).
__global__ __launch_bounds__(256)
void rho_loss_kernel(const float* __restrict__ x, const u64* __restrict__ table,
                     float* __restrict__ out) {
    __shared__ float partial[4];
    const int lane = threadIdx.x & 63;
    const int wave = threadIdx.x >> 6;
    const int waveGlobal = blockIdx.x * 4 + wave;   // 2048 waves

    u64 pk[8];
#pragma unroll
    for (int r8 = 0; r8 < 8; ++r8) pk[r8] = table[waveGlobal * 8 + r8];

    float local = 0.f;
#pragma unroll
    for (int r8 = 0; r8 < 8; ++r8) {
        const int row = waveGlobal * 8 + r8;
        const int nb  = (int)(~(unsigned)(pk[r8] & 0xFFFFFFFFu));

        const float4* xr = (const float4*)(x + (size_t)row * DIM);
        const float4* xn = (const float4*)(x + (size_t)nb  * DIM);
        float s = 0.f;
#pragma unroll
        for (int tt = 0; tt < 2; ++tt) {
            float4 a = xr[lane * 2 + tt];
            float4 b = xn[lane * 2 + tt];
            float d0 = a.x - b.x + 1e-6f;
            float d1 = a.y - b.y + 1e-6f;
            float d2 = a.z - b.z + 1e-6f;
            float d3 = a.w - b.w + 1e-6f;
            s += d0 * d0 + d1 * d1 + d2 * d2 + d3 * d3;
        }
#pragma unroll
        for (int m = 1; m < 64; m <<= 1) s += __shfl_xor(s, m, 64);

        if (lane == 0) {
            float rho = sqrtf(s);
            local += logf(rho + 1e-8f);
        }
    }
    if (lane == 0) partial[wave] = local;
    __syncthreads();
    if (threadIdx.x == 0) {
        const float s = partial[0] + partial[1] + partial[2] + partial[3];
        atomicAdd(out, -s * (1.0f / 16384.0f));
    }
}

extern "C" void kernel_launch(void* const* d_in, const int* in_sizes, int n_in,
                              void* d_out, int out_size, void* d_ws, size_t ws_size,
                              hipStream_t stream) {
    const float* x = (const float*)d_in[0];

    // Workspace: [0, 8 MiB) fp8 x (K-permuted); then 16384 x u64 argmax table.
    u8*    xb    = (u8*)d_ws;
    u64*   table = (u64*)((char*)d_ws + (size_t)N_ROWS * DIM);
    float* out   = (float*)d_out;

    convert_fp8_kernel<<<2048, 256, 0, stream>>>(x, (unsigned*)xb, table, out);
    argmax_dots_kernel<<<8256, 256, 0, stream>>>(xb, table);
    rho_loss_kernel<<<512, 256, 0, stream>>>(x, table, out);
}